// Round 12
// baseline (272.276 us; speedup 1.0000x reference)
//
#include <hip/hip_runtime.h>

typedef __attribute__((ext_vector_type(4))) int   i32x4;
typedef __attribute__((ext_vector_type(4))) float f32x4;

#define HDIM 16
#define MDIM 2048
#define NDIM 2048
#define KDIM 128

// ---------------------------------------------------------------------------
// Prep kernel (proven r5/r7): packs A and B (int32 0..126 -> int8, 16
// elems/thr) and copies the scale_out passthrough tail. One launch.
// ---------------------------------------------------------------------------
__global__ __launch_bounds__(256)
void prep_pack_tail(const int* __restrict__ A,
                    const int* __restrict__ B,
                    const float* __restrict__ sO,
                    unsigned char* __restrict__ A8,
                    unsigned char* __restrict__ B8,
                    float* __restrict__ out_tail) {
    const int nPackA = HDIM * MDIM * KDIM / 16;   // 262,144 threads for A
    int t = blockIdx.x * blockDim.x + threadIdx.x;

    const int* src;
    unsigned char* dst;
    int idx;
    if (t < nPackA) { src = A; dst = A8; idx = t; }
    else            { src = B; dst = B8; idx = t - nPackA; }

    const i32x4* s = reinterpret_cast<const i32x4*>(src) + (size_t)idx * 4;
    i32x4 v0 = s[0], v1 = s[1], v2 = s[2], v3 = s[3];
    i32x4 o;
    o.x = v0.x | (v0.y << 8) | (v0.z << 16) | (v0.w << 24);
    o.y = v1.x | (v1.y << 8) | (v1.z << 16) | (v1.w << 24);
    o.z = v2.x | (v2.y << 8) | (v2.z << 16) | (v2.w << 24);
    o.w = v3.x | (v3.y << 8) | (v3.z << 16) | (v3.w << 24);
    reinterpret_cast<i32x4*>(dst)[idx] = o;

    if (t < HDIM * MDIM)                           // 32,768 tail floats
        out_tail[t] = sO[t];
}

// ---------------------------------------------------------------------------
// DIAGNOSTIC round: exact r7 GEMM body, repeated reps=8 per dispatch
// (idempotent; asm memory barrier forces true replays). Dispatch ~247 us
// > harness fills (~155) -> its counter row FINALLY becomes visible.
// r8's reps=4 missed top-5 by ~10 us. Revert to reps=1 next round.
//
// Body (r7-proven): tile 128x256, 512 thr = 8 waves 2x4, wave = 64x64 via
// 4x4 fragments of v_mfma_i32_16x16x64_i8, swapped operands -> lane
// (fr=lane&15, kg=lane>>4) holds C[m=..+fr][n=..+kg*4+r] -> f32x4 stores.
// Chunked XCD swizzle. Epilogue: clamp(rint(acc*((sA/sO)*sB)), +/-127).
// ---------------------------------------------------------------------------
__global__ __launch_bounds__(512)
void gemm_i8_fused(const unsigned char* __restrict__ A8,
                   const unsigned char* __restrict__ B8,
                   const float* __restrict__ sA,
                   const float* __restrict__ sB,
                   const float* __restrict__ sO,
                   float* __restrict__ out,
                   int reps) {
    // chunked XCD swizzle: nwg = 2048, 8 XCDs, 256 per chunk
    const int i = blockIdx.x;
    const int w = (i & 7) * 256 + (i >> 3);
    const int bx = w & 7;            // 8 col-tiles of 256
    const int by = (w >> 3) & 15;    // 16 row-tiles of 128
    const int h  = w >> 7;

    const int bm = by * 128;
    const int bn = bx * 256;
    const int tid  = threadIdx.x;
    const int wave = tid >> 6;
    const int lane = tid & 63;
    const int wm = (wave >> 2) * 64;
    const int wn = (wave & 3) * 64;
    const int fr = lane & 15;
    const int kg = lane >> 4;

    const unsigned char* Ah = A8 + (size_t)h * MDIM * KDIM;
    const unsigned char* Bh = B8 + (size_t)h * NDIM * KDIM;
    const float* sAh = sA + h * MDIM;
    const float* sBh = sB + h * NDIM;
    const float* sOh = sO + h * MDIM;

    for (int rep = 0; rep < reps; ++rep) {
        i32x4 acc[4][4];
#pragma unroll
        for (int mi = 0; mi < 4; ++mi)
#pragma unroll
            for (int ni = 0; ni < 4; ++ni)
                acc[mi][ni] = (i32x4){0, 0, 0, 0};

#pragma unroll
        for (int ks = 0; ks < 2; ++ks) {
            const int kb = ks * 64 + kg * 16;
            i32x4 af[4], bf[4];
#pragma unroll
            for (int mi = 0; mi < 4; ++mi)
                af[mi] = *reinterpret_cast<const i32x4*>(
                    Ah + (size_t)(bm + wm + mi * 16 + fr) * KDIM + kb);
#pragma unroll
            for (int ni = 0; ni < 4; ++ni)
                bf[ni] = *reinterpret_cast<const i32x4*>(
                    Bh + (size_t)(bn + wn + ni * 16 + fr) * KDIM + kb);
#pragma unroll
            for (int mi = 0; mi < 4; ++mi)
#pragma unroll
                for (int ni = 0; ni < 4; ++ni)
                    acc[mi][ni] = __builtin_amdgcn_mfma_i32_16x16x64_i8(
                        bf[ni], af[mi], acc[mi][ni], 0, 0, 0);
        }

        float smv[4];
#pragma unroll
        for (int mi = 0; mi < 4; ++mi) {
            const int m = bm + wm + mi * 16 + fr;
            smv[mi] = sAh[m] / sOh[m];
        }
        f32x4 sbv[4];
#pragma unroll
        for (int ni = 0; ni < 4; ++ni)
            sbv[ni] = *reinterpret_cast<const f32x4*>(sBh + bn + wn + ni * 16 + kg * 4);

#pragma unroll
        for (int mi = 0; mi < 4; ++mi) {
            const int m = bm + wm + mi * 16 + fr;
            float* orow = out + ((size_t)h * MDIM + m) * NDIM + bn + wn + kg * 4;
#pragma unroll
            for (int ni = 0; ni < 4; ++ni) {
                f32x4 o;
#pragma unroll
                for (int r = 0; r < 4; ++r) {
                    float c = (float)acc[mi][ni][r] * (smv[mi] * sbv[ni][r]);
                    float rv = rintf(c);
                    o[r] = fminf(fmaxf(rv, -127.0f), 127.0f);
                }
                *reinterpret_cast<f32x4*>(orow + ni * 16) = o;
            }
        }
        asm volatile("" ::: "memory");   // force true replay each pass
    }
}

extern "C" void kernel_launch(void* const* d_in, const int* in_sizes, int n_in,
                              void* d_out, int out_size, void* d_ws, size_t ws_size,
                              hipStream_t stream) {
    const int*   A  = (const int*)d_in[0];
    const int*   B  = (const int*)d_in[1];
    const float* sA = (const float*)d_in[2];
    const float* sB = (const float*)d_in[3];
    const float* sO = (const float*)d_in[4];
    float* out = (float*)d_out;

    unsigned char* A8 = (unsigned char*)d_ws;
    unsigned char* B8 = A8 + (size_t)HDIM * MDIM * KDIM;

    const int packThreads = 2 * HDIM * MDIM * KDIM / 16;   // 524,288
    prep_pack_tail<<<packThreads / 256, 256, 0, stream>>>(
        A, B, sO, A8, B8, out + (size_t)HDIM * MDIM * NDIM);

    gemm_i8_fused<<<2048, 512, 0, stream>>>(A8, B8, sA, sB, sO, out, 8);
}

// Round 13
// 141.597 us; speedup vs baseline: 1.9229x; 1.9229x over previous
//
#include <hip/hip_runtime.h>
#include <hip/hip_cooperative_groups.h>

namespace cg = cooperative_groups;

typedef __attribute__((ext_vector_type(4))) int   i32x4;
typedef __attribute__((ext_vector_type(4))) float f32x4;

#define HDIM 16
#define MDIM 2048
#define NDIM 2048
#define KDIM 128

// Pack 4 int32 (values 0..126, high bytes zero) into one dword of 4 int8.
__device__ inline int pack4(i32x4 v) {
    return v.x | (v.y << 8) | (v.z << 16) | (v.w << 24);
}

// ---------------------------------------------------------------------------
// Cooperative single-launch: phase 1 packs A,B (int32 -> int8 in d_ws) and
// writes the scale_out tail; grid.sync(); phase 2 sweeps the 2048 GEMM tiles
// with the proven r7 body. Eliminates the prep->GEMM launch boundary and its
// full pipeline drain (r4->r5 measured that boundary class at ~13.5 us).
//
// Phase-2 body (r7-proven): tile 128x256, 8 waves 2x4, wave = 64x64 via 4x4
// fragments of v_mfma_i32_16x16x64_i8, K = 2 unrolled steps, SWAPPED
// operands -> lane (fr=lane&15, kg=lane>>4) holds C[m=..+fr][n=..+kg*4+r],
// r=0..3 consecutive n -> f32x4 coalesced stores. Scale loads hoisted ABOVE
// the MFMA section so their latency hides under fragment loads + MFMA
// (r12 PMC: latency-bound — VALUBusy 25%, MfmaUtil 10%, HBM 19%).
// Tile sweep t = b + k*grid keeps XCD chunk affinity (t&7 == b&7 when
// grid % 8 == 0); at each k the 64 blocks of an XCD cover a contiguous
// 64-tile window of its output slab (write locality).
// Epilogue: c = clamp(rint(acc * ((sA[m]/sO[m]) * sB[n])), -127, 127),
// stored as float32 (harness reads d_out as float32).
// ---------------------------------------------------------------------------
__global__ __launch_bounds__(512, 4)
void gemm_i8_coop(const int* __restrict__ A,
                  const int* __restrict__ B,
                  const float* __restrict__ sA,
                  const float* __restrict__ sB,
                  const float* __restrict__ sO,
                  float* __restrict__ out,
                  unsigned char* __restrict__ A8,
                  unsigned char* __restrict__ B8) {
    const int b   = blockIdx.x;
    const int tid = threadIdx.x;
    const int nthreads = gridDim.x * blockDim.x;
    const int gid = b * blockDim.x + tid;

    // ---- Phase 1: pack A and B, write scale_out tail ----
    const int nPackA = HDIM * MDIM * KDIM / 16;   // 262,144 units each
    for (int u = gid; u < nPackA; u += nthreads) {
        const i32x4* s = reinterpret_cast<const i32x4*>(A) + (size_t)u * 4;
        i32x4 v0 = s[0], v1 = s[1], v2 = s[2], v3 = s[3];
        reinterpret_cast<i32x4*>(A8)[u] =
            (i32x4){pack4(v0), pack4(v1), pack4(v2), pack4(v3)};
        const i32x4* sb2 = reinterpret_cast<const i32x4*>(B) + (size_t)u * 4;
        i32x4 w0 = sb2[0], w1 = sb2[1], w2 = sb2[2], w3 = sb2[3];
        reinterpret_cast<i32x4*>(B8)[u] =
            (i32x4){pack4(w0), pack4(w1), pack4(w2), pack4(w3)};
    }
    float* out_tail = out + (size_t)HDIM * MDIM * NDIM;
    for (int u = gid; u < HDIM * MDIM; u += nthreads)
        out_tail[u] = sO[u];

    cg::this_grid().sync();

    // ---- Phase 2: GEMM tile sweep ----
    const int wave = tid >> 6;
    const int lane = tid & 63;
    const int wm = (wave >> 2) * 64;   // 2 wave-rows of 64
    const int wn = (wave & 3) * 64;    // 4 wave-cols of 64
    const int fr = lane & 15;          // fragment row; out row m
    const int kg = lane >> 4;          // 0..3 k-group; out n-subchunk

    for (int t = b; t < 2048; t += gridDim.x) {
        // chunked XCD mapping (same as r7): chunk = t&7, index = t>>3
        const int w  = (t & 7) * 256 + (t >> 3);
        const int bx = w & 7;            // 8 col-tiles of 256
        const int by = (w >> 3) & 15;    // 16 row-tiles of 128
        const int h  = w >> 7;

        const int bm = by * 128;
        const int bn = bx * 256;

        const unsigned char* Ah = A8 + (size_t)h * MDIM * KDIM;
        const unsigned char* Bh = B8 + (size_t)h * NDIM * KDIM;
        const float* sAh = sA + h * MDIM;
        const float* sBh = sB + h * NDIM;
        const float* sOh = sO + h * MDIM;

        // Hoisted epilogue scales: issue these loads FIRST so their latency
        // hides under the fragment loads + MFMA below.
        float smv[4];
#pragma unroll
        for (int mi = 0; mi < 4; ++mi) {
            const int m = bm + wm + mi * 16 + fr;
            smv[mi] = sAh[m] / sOh[m];          // reference op order
        }
        f32x4 sbv[4];
#pragma unroll
        for (int ni = 0; ni < 4; ++ni)
            sbv[ni] = *reinterpret_cast<const f32x4*>(sBh + bn + wn + ni * 16 + kg * 4);

        i32x4 acc[4][4];
#pragma unroll
        for (int mi = 0; mi < 4; ++mi)
#pragma unroll
            for (int ni = 0; ni < 4; ++ni)
                acc[mi][ni] = (i32x4){0, 0, 0, 0};

#pragma unroll
        for (int ks = 0; ks < 2; ++ks) {
            const int kb = ks * 64 + kg * 16;
            i32x4 af[4], bf[4];
#pragma unroll
            for (int mi = 0; mi < 4; ++mi)
                af[mi] = *reinterpret_cast<const i32x4*>(
                    Ah + (size_t)(bm + wm + mi * 16 + fr) * KDIM + kb);
#pragma unroll
            for (int ni = 0; ni < 4; ++ni)
                bf[ni] = *reinterpret_cast<const i32x4*>(
                    Bh + (size_t)(bn + wn + ni * 16 + fr) * KDIM + kb);
#pragma unroll
            for (int mi = 0; mi < 4; ++mi)
#pragma unroll
                for (int ni = 0; ni < 4; ++ni)
                    acc[mi][ni] = __builtin_amdgcn_mfma_i32_16x16x64_i8(
                        bf[ni], af[mi], acc[mi][ni], 0, 0, 0);  // swapped -> C^T
        }

#pragma unroll
        for (int mi = 0; mi < 4; ++mi) {
            const int m = bm + wm + mi * 16 + fr;
            float* orow = out + ((size_t)h * MDIM + m) * NDIM + bn + wn + kg * 4;
#pragma unroll
            for (int ni = 0; ni < 4; ++ni) {
                f32x4 o;
#pragma unroll
                for (int r = 0; r < 4; ++r) {
                    float c = (float)acc[mi][ni][r] * (smv[mi] * sbv[ni][r]);
                    float rv = rintf(c);                       // RNE == np.round
                    o[r] = fminf(fmaxf(rv, -127.0f), 127.0f);
                }
                *reinterpret_cast<f32x4*>(orow + ni * 16) = o;
            }
        }
    }
}

extern "C" void kernel_launch(void* const* d_in, const int* in_sizes, int n_in,
                              void* d_out, int out_size, void* d_ws, size_t ws_size,
                              hipStream_t stream) {
    const int*   A  = (const int*)d_in[0];
    const int*   B  = (const int*)d_in[1];
    const float* sA = (const float*)d_in[2];
    const float* sB = (const float*)d_in[3];
    const float* sO = (const float*)d_in[4];
    float* out = (float*)d_out;

    unsigned char* A8 = (unsigned char*)d_ws;
    unsigned char* B8 = A8 + (size_t)HDIM * MDIM * KDIM;

    // Host-side occupancy query (no stream ops; capture-safe).
    int nb = 0;
    hipOccupancyMaxActiveBlocksPerMultiprocessor(&nb, gemm_i8_coop, 512, 0);
    if (nb < 1) nb = 1;
    int grid = nb * 256;               // co-resident capacity
    if (grid > 512) grid = 512;        // 512 x 512thr covers pack exactly
    grid &= ~7;                        // keep XCD chunk affinity (mult of 8)
    if (grid < 8) grid = 8;

    void* args[] = {(void*)&A, (void*)&B, (void*)&sA, (void*)&sB,
                    (void*)&sO, (void*)&out, (void*)&A8, (void*)&B8};
    hipLaunchCooperativeKernel((void*)gemm_i8_coop, dim3(grid), dim3(512),
                               args, 0, stream);
}

// Round 14
// 94.543 us; speedup vs baseline: 2.8799x; 1.4977x over previous
//
#include <hip/hip_runtime.h>

typedef __attribute__((ext_vector_type(4))) int   i32x4;
typedef __attribute__((ext_vector_type(4))) float f32x4;

#define HDIM 16
#define MDIM 2048
#define NDIM 2048
#define KDIM 128

// ---------------------------------------------------------------------------
// Prep kernel (proven r5/r7): packs A and B (int32 0..126 -> int8, 16
// elems/thr) and copies the scale_out passthrough tail. One launch.
// ---------------------------------------------------------------------------
__global__ __launch_bounds__(256)
void prep_pack_tail(const int* __restrict__ A,
                    const int* __restrict__ B,
                    const float* __restrict__ sO,
                    unsigned char* __restrict__ A8,
                    unsigned char* __restrict__ B8,
                    float* __restrict__ out_tail) {
    const int nPackA = HDIM * MDIM * KDIM / 16;   // 262,144 threads for A
    int t = blockIdx.x * blockDim.x + threadIdx.x;

    const int* src;
    unsigned char* dst;
    int idx;
    if (t < nPackA) { src = A; dst = A8; idx = t; }
    else            { src = B; dst = B8; idx = t - nPackA; }

    const i32x4* s = reinterpret_cast<const i32x4*>(src) + (size_t)idx * 4;
    i32x4 v0 = s[0], v1 = s[1], v2 = s[2], v3 = s[3];
    i32x4 o;
    o.x = v0.x | (v0.y << 8) | (v0.z << 16) | (v0.w << 24);
    o.y = v1.x | (v1.y << 8) | (v1.z << 16) | (v1.w << 24);
    o.z = v2.x | (v2.y << 8) | (v2.z << 16) | (v2.w << 24);
    o.w = v3.x | (v3.y << 8) | (v3.z << 16) | (v3.w << 24);
    reinterpret_cast<i32x4*>(dst)[idx] = o;

    if (t < HDIM * MDIM)                           // 32,768 tail floats
        out_tail[t] = sO[t];
}

// ---------------------------------------------------------------------------
// WIDE-BLOCK batched i8 GEMM on pre-packed int8: C[h] = A[h](MxK)*B[h]^T.
//
// Change vs r7 (85.2 us): workgroup 512 -> 1024 threads (16 waves), tile
// 128x256 -> 256x256 with the SAME proven 64x64 per-wave body. Mechanism
// (r12 PMC: Occupancy 26% = 2 waves/SIMD, latency-bound): a 1024-thread
// workgroup dispatches 16 waves to one CU as a unit -> guaranteed 4
// waves/SIMD co-resident, 2x the measured steady state, hiding the
// L1-missing 16B fragment loads and the store stream. Per-wave VGPR
// unchanged (~84, well under the 512-cap implied by 1024-thr blocks).
//
// Grid 1024, chunked XCD swizzle (8 XCDs x 128): XCD k owns h=2k,2k+1
// (packed working set ~1 MB << 4 MB L2). Wave grid 4x4; per wave:
// 2 K-steps of v_mfma_i32_16x16x64_i8, SWAPPED operands -> lane
// (fr=lane&15, kg=lane>>4) holds C[m=..+fr][n=..+kg*4+r], r=0..3
// consecutive n -> f32x4 coalesced stores.
// Epilogue (bit-exact): c = clamp(rint(acc * ((sA[m]/sO[m]) * sB[n])),
// -127, 127), stored as float32 (harness reads d_out as float32).
// ---------------------------------------------------------------------------
__global__ __launch_bounds__(1024)
void gemm_i8_fused(const unsigned char* __restrict__ A8,
                   const unsigned char* __restrict__ B8,
                   const float* __restrict__ sA,
                   const float* __restrict__ sB,
                   const float* __restrict__ sO,
                   float* __restrict__ out) {
    // chunked XCD swizzle: nwg = 1024, 8 XCDs, 128 per chunk
    const int i = blockIdx.x;
    const int w = (i & 7) * 128 + (i >> 3);
    const int bx = w & 7;            // 8 col-tiles of 256
    const int by = (w >> 3) & 7;     // 8 row-tiles of 256
    const int h  = w >> 6;

    const int bm = by * 256;
    const int bn = bx * 256;
    const int tid  = threadIdx.x;
    const int wave = tid >> 6;         // 0..15
    const int lane = tid & 63;
    const int wm = (wave >> 2) * 64;   // 4 wave-rows of 64
    const int wn = (wave & 3) * 64;    // 4 wave-cols of 64
    const int fr = lane & 15;          // fragment row; out row m
    const int kg = lane >> 4;          // 0..3 k-group; out n-subchunk

    const unsigned char* Ah = A8 + (size_t)h * MDIM * KDIM;
    const unsigned char* Bh = B8 + (size_t)h * NDIM * KDIM;

    i32x4 acc[4][4];
#pragma unroll
    for (int mi = 0; mi < 4; ++mi)
#pragma unroll
        for (int ni = 0; ni < 4; ++ni)
            acc[mi][ni] = (i32x4){0, 0, 0, 0};

#pragma unroll
    for (int ks = 0; ks < 2; ++ks) {
        const int kb = ks * 64 + kg * 16;   // byte offset of this lane's 16B chunk
        i32x4 af[4], bf[4];
#pragma unroll
        for (int mi = 0; mi < 4; ++mi)
            af[mi] = *reinterpret_cast<const i32x4*>(
                Ah + (size_t)(bm + wm + mi * 16 + fr) * KDIM + kb);
#pragma unroll
        for (int ni = 0; ni < 4; ++ni)
            bf[ni] = *reinterpret_cast<const i32x4*>(
                Bh + (size_t)(bn + wn + ni * 16 + fr) * KDIM + kb);
#pragma unroll
        for (int mi = 0; mi < 4; ++mi)
#pragma unroll
            for (int ni = 0; ni < 4; ++ni)
                acc[mi][ni] = __builtin_amdgcn_mfma_i32_16x16x64_i8(
                    bf[ni], af[mi], acc[mi][ni], 0, 0, 0);  // swapped -> C^T frag
    }

    // Epilogue. Lane holds row m = bm+wm+mi*16+fr,
    // cols n = bn+wn+ni*16+kg*4 .. +3 (regs r=0..3 consecutive n).
    const float* sAh = sA + h * MDIM;
    const float* sBh = sB + h * NDIM;
    const float* sOh = sO + h * MDIM;

    float smv[4];
#pragma unroll
    for (int mi = 0; mi < 4; ++mi) {
        const int m = bm + wm + mi * 16 + fr;
        smv[mi] = sAh[m] / sOh[m];          // reference op order: sA/sO first
    }
    f32x4 sbv[4];
#pragma unroll
    for (int ni = 0; ni < 4; ++ni)
        sbv[ni] = *reinterpret_cast<const f32x4*>(sBh + bn + wn + ni * 16 + kg * 4);

#pragma unroll
    for (int mi = 0; mi < 4; ++mi) {
        const int m = bm + wm + mi * 16 + fr;
        float* orow = out + ((size_t)h * MDIM + m) * NDIM + bn + wn + kg * 4;
#pragma unroll
        for (int ni = 0; ni < 4; ++ni) {
            f32x4 o;
#pragma unroll
            for (int r = 0; r < 4; ++r) {
                float c = (float)acc[mi][ni][r] * (smv[mi] * sbv[ni][r]);
                float rv = rintf(c);                       // RNE == np.round
                o[r] = fminf(fmaxf(rv, -127.0f), 127.0f);
            }
            *reinterpret_cast<f32x4*>(orow + ni * 16) = o;
        }
    }
}

extern "C" void kernel_launch(void* const* d_in, const int* in_sizes, int n_in,
                              void* d_out, int out_size, void* d_ws, size_t ws_size,
                              hipStream_t stream) {
    const int*   A  = (const int*)d_in[0];
    const int*   B  = (const int*)d_in[1];
    const float* sA = (const float*)d_in[2];
    const float* sB = (const float*)d_in[3];
    const float* sO = (const float*)d_in[4];
    float* out = (float*)d_out;

    unsigned char* A8 = (unsigned char*)d_ws;
    unsigned char* B8 = A8 + (size_t)HDIM * MDIM * KDIM;

    const int packThreads = 2 * HDIM * MDIM * KDIM / 16;   // 524,288
    prep_pack_tail<<<packThreads / 256, 256, 0, stream>>>(
        A, B, sO, A8, B8, out + (size_t)HDIM * MDIM * NDIM);

    gemm_i8_fused<<<1024, 1024, 0, stream>>>(A8, B8, sA, sB, sO, out);
}

// Round 15
// 74.350 us; speedup vs baseline: 3.6621x; 1.2716x over previous
//
#include <hip/hip_runtime.h>

typedef __attribute__((ext_vector_type(4))) int   i32x4;
typedef __attribute__((ext_vector_type(4))) float f32x4;

#define HDIM 16
#define MDIM 2048
#define NDIM 2048
#define KDIM 128

// Pack 4 int32 (values 0..126, high bytes zero) into one dword of 4 int8.
__device__ inline int pack4(i32x4 v) {
    return v.x | (v.y << 8) | (v.z << 16) | (v.w << 24);
}

// ---------------------------------------------------------------------------
// Prep: pack int32 -> int8 AND re-layout into MFMA-fragment-linear order:
//   per 16-row rowgroup (2048 B): [ks=2][kg=4][fr=16][16B]
// so a GEMM wave's fragment load is ONE dense 1 KB burst (lane*16), instead
// of 16 scattered 64-B segments over 2 KB (the r7 gather — 2x line traffic,
// 16 miss-segments/instruction; the measured latency-boundness driver).
//
// 256 blocks x 256 threads. Block b<128: A slab b; else B slab b-128.
// Slab = 256 rows = 16 rowgroups = 32 KB packed output (contiguous).
//  read phase : thread t packs row t of the slab (128 int32, 8x dwordx4,
//               coalesced across the wave) into LDS (32 KB, padded rows).
//  write phase: per j, thread t writes 16 B at j*4096 + t*16 -> each
//               instruction writes a dense 4 KB block run (fully coalesced).
// Also copies the scale_out passthrough tail (128 floats/block).
// ---------------------------------------------------------------------------
__global__ __launch_bounds__(256)
void prep_relayout(const int* __restrict__ A,
                   const int* __restrict__ B,
                   const float* __restrict__ sO,
                   unsigned char* __restrict__ A8T,
                   unsigned char* __restrict__ B8T,
                   float* __restrict__ out_tail) {
    __shared__ int lds[256][36];   // 256 rows x 128 B packed, +16B pad (144B row, 16-aligned)

    const int b = blockIdx.x;
    const int t = threadIdx.x;

    const bool isB = (b >= 128);
    const int s = isB ? (b - 128) : b;            // slab id 0..127
    const int* __restrict__ src = isB ? B : A;
    unsigned char* __restrict__ dst = isB ? B8T : A8T;

    // Output 1 tail: scale_out passthrough (exact).
    if (t < 128) out_tail[b * 128 + t] = sO[b * 128 + t];

    // ---- read + pack: row t of the slab ----
    const i32x4* p = reinterpret_cast<const i32x4*>(src + ((size_t)s * 256 + t) * 128);
#pragma unroll
    for (int ch = 0; ch < 8; ++ch) {
        i32x4 v0 = p[ch * 4], v1 = p[ch * 4 + 1], v2 = p[ch * 4 + 2], v3 = p[ch * 4 + 3];
        *reinterpret_cast<i32x4*>(&lds[t][ch * 4]) =
            (i32x4){pack4(v0), pack4(v1), pack4(v2), pack4(v3)};
    }
    __syncthreads();

    // ---- write fragment-linear: out byte o = j*4096 + t*16 ----
    // o -> rowgrp = j*2 + (t>>7), ks = (t>>6)&1, kg = (t>>4)&3, fr = t&15
    const int fr = t & 15, kg = (t >> 4) & 3, ks = (t >> 6) & 1, rg0 = t >> 7;
    const int cc = ks * 4 + kg;                   // source K-chunk 0..7
    unsigned char* outp = dst + (size_t)s * 32768 + t * 16;
#pragma unroll
    for (int j = 0; j < 8; ++j) {
        const int row = (j * 2 + rg0) * 16 + fr;
        *reinterpret_cast<i32x4*>(outp + j * 4096) =
            *reinterpret_cast<const i32x4*>(&lds[row][cc * 4]);
    }
}

// ---------------------------------------------------------------------------
// Batched i8 GEMM on fragment-linear packed int8 (r7 chassis, dense loads).
// Tile 128x256, 512 threads = 8 waves 2x4; wave = 64x64 via 4x4 fragments
// of v_mfma_i32_16x16x64_i8, K = 2 unrolled steps. Fragment load is now
// base + rowgrp*2048 + ks*1024 + lane*16 : one contiguous 1 KB wave burst.
// SWAPPED operands -> lane (fr=lane&15, kg=lane>>4) holds
// C[m=..+fr][n=..+kg*4+r], r=0..3 consecutive n -> f32x4 coalesced stores.
// Grid 2048, chunked XCD swizzle (8 XCDs x 256, same-h resident slabs).
// Epilogue (bit-exact): c = clamp(rint(acc * ((sA[m]/sO[m]) * sB[n])),
// -127, 127), stored as float32 (harness reads d_out as float32).
// ---------------------------------------------------------------------------
__global__ __launch_bounds__(512)
void gemm_i8_fused(const unsigned char* __restrict__ A8T,
                   const unsigned char* __restrict__ B8T,
                   const float* __restrict__ sA,
                   const float* __restrict__ sB,
                   const float* __restrict__ sO,
                   float* __restrict__ out) {
    // chunked XCD swizzle: nwg = 2048, 8 XCDs, 256 per chunk
    const int i = blockIdx.x;
    const int w = (i & 7) * 256 + (i >> 3);
    const int bx = w & 7;            // 8 col-tiles of 256
    const int by = (w >> 3) & 15;    // 16 row-tiles of 128
    const int h  = w >> 7;

    const int bm = by * 128;
    const int bn = bx * 256;
    const int tid  = threadIdx.x;
    const int wave = tid >> 6;
    const int lane = tid & 63;
    const int wm = (wave >> 2) * 64;   // 2 wave-rows of 64
    const int wn = (wave & 3) * 64;    // 4 wave-cols of 64
    const int fr = lane & 15;          // out row m sub-index
    const int kg = lane >> 4;          // out n-subchunk

    const unsigned char* AhT = A8T + (size_t)h * MDIM * KDIM;
    const unsigned char* BhT = B8T + (size_t)h * NDIM * KDIM;
    const int abase = (bm + wm) >> 4;  // rowgroup base for this wave's A rows
    const int bbase = (bn + wn) >> 4;  // rowgroup base for this wave's B rows

    i32x4 acc[4][4];
#pragma unroll
    for (int mi = 0; mi < 4; ++mi)
#pragma unroll
        for (int ni = 0; ni < 4; ++ni)
            acc[mi][ni] = (i32x4){0, 0, 0, 0};

#pragma unroll
    for (int ks = 0; ks < 2; ++ks) {
        i32x4 af[4], bf[4];
#pragma unroll
        for (int mi = 0; mi < 4; ++mi)
            af[mi] = *reinterpret_cast<const i32x4*>(
                AhT + (size_t)(abase + mi) * 2048 + ks * 1024 + lane * 16);
#pragma unroll
        for (int ni = 0; ni < 4; ++ni)
            bf[ni] = *reinterpret_cast<const i32x4*>(
                BhT + (size_t)(bbase + ni) * 2048 + ks * 1024 + lane * 16);
#pragma unroll
        for (int mi = 0; mi < 4; ++mi)
#pragma unroll
            for (int ni = 0; ni < 4; ++ni)
                acc[mi][ni] = __builtin_amdgcn_mfma_i32_16x16x64_i8(
                    bf[ni], af[mi], acc[mi][ni], 0, 0, 0);  // swapped -> C^T frag
    }

    // Epilogue. Lane holds row m = bm+wm+mi*16+fr,
    // cols n = bn+wn+ni*16+kg*4 .. +3 (regs r=0..3 consecutive n).
    const float* sAh = sA + h * MDIM;
    const float* sBh = sB + h * NDIM;
    const float* sOh = sO + h * MDIM;

    float smv[4];
#pragma unroll
    for (int mi = 0; mi < 4; ++mi) {
        const int m = bm + wm + mi * 16 + fr;
        smv[mi] = sAh[m] / sOh[m];          // reference op order: sA/sO first
    }
    f32x4 sbv[4];
#pragma unroll
    for (int ni = 0; ni < 4; ++ni)
        sbv[ni] = *reinterpret_cast<const f32x4*>(sBh + bn + wn + ni * 16 + kg * 4);

#pragma unroll
    for (int mi = 0; mi < 4; ++mi) {
        const int m = bm + wm + mi * 16 + fr;
        float* orow = out + ((size_t)h * MDIM + m) * NDIM + bn + wn + kg * 4;
#pragma unroll
        for (int ni = 0; ni < 4; ++ni) {
            f32x4 o;
#pragma unroll
            for (int r = 0; r < 4; ++r) {
                float c = (float)acc[mi][ni][r] * (smv[mi] * sbv[ni][r]);
                float rv = rintf(c);                       // RNE == np.round
                o[r] = fminf(fmaxf(rv, -127.0f), 127.0f);
            }
            *reinterpret_cast<f32x4*>(orow + ni * 16) = o;
        }
    }
}

extern "C" void kernel_launch(void* const* d_in, const int* in_sizes, int n_in,
                              void* d_out, int out_size, void* d_ws, size_t ws_size,
                              hipStream_t stream) {
    const int*   A  = (const int*)d_in[0];
    const int*   B  = (const int*)d_in[1];
    const float* sA = (const float*)d_in[2];
    const float* sB = (const float*)d_in[3];
    const float* sO = (const float*)d_in[4];
    float* out = (float*)d_out;

    unsigned char* A8T = (unsigned char*)d_ws;
    unsigned char* B8T = A8T + (size_t)HDIM * MDIM * KDIM;

    prep_relayout<<<256, 256, 0, stream>>>(
        A, B, sO, A8T, B8T, out + (size_t)HDIM * MDIM * NDIM);

    gemm_i8_fused<<<2048, 512, 0, stream>>>(A8T, B8T, sA, sB, sO, out);
}

// Round 16
// 70.653 us; speedup vs baseline: 3.8537x; 1.0523x over previous
//
#include <hip/hip_runtime.h>

typedef __attribute__((ext_vector_type(4))) int   i32x4;
typedef __attribute__((ext_vector_type(4))) float f32x4;

#define HDIM 16
#define MDIM 2048
#define NDIM 2048
#define KDIM 128

// Pack 4 int32 (values 0..126, high bytes zero) into one dword of 4 int8.
__device__ inline int pack4(i32x4 v) {
    return v.x | (v.y << 8) | (v.z << 16) | (v.w << 24);
}

// ---------------------------------------------------------------------------
// Prep (r15-proven): pack int32 -> int8 AND re-layout into MFMA-fragment-
// linear order (per 16-row rowgroup: [ks=2][kg=4][fr=16][16B]) so GEMM
// fragment loads are single dense 1 KB wave bursts.
// ---------------------------------------------------------------------------
__global__ __launch_bounds__(256)
void prep_relayout(const int* __restrict__ A,
                   const int* __restrict__ B,
                   const float* __restrict__ sO,
                   unsigned char* __restrict__ A8T,
                   unsigned char* __restrict__ B8T,
                   float* __restrict__ out_tail) {
    __shared__ int lds[256][36];   // 256 rows x 128 B packed, +16 B pad

    const int b = blockIdx.x;
    const int t = threadIdx.x;

    const bool isB = (b >= 128);
    const int s = isB ? (b - 128) : b;            // slab id 0..127
    const int* __restrict__ src = isB ? B : A;
    unsigned char* __restrict__ dst = isB ? B8T : A8T;

    if (t < 128) out_tail[b * 128 + t] = sO[b * 128 + t];

    const i32x4* p = reinterpret_cast<const i32x4*>(src + ((size_t)s * 256 + t) * 128);
#pragma unroll
    for (int ch = 0; ch < 8; ++ch) {
        i32x4 v0 = p[ch * 4], v1 = p[ch * 4 + 1], v2 = p[ch * 4 + 2], v3 = p[ch * 4 + 3];
        *reinterpret_cast<i32x4*>(&lds[t][ch * 4]) =
            (i32x4){pack4(v0), pack4(v1), pack4(v2), pack4(v3)};
    }
    __syncthreads();

    const int fr = t & 15, kg = (t >> 4) & 3, ks = (t >> 6) & 1, rg0 = t >> 7;
    const int cc = ks * 4 + kg;                   // source K-chunk 0..7
    unsigned char* outp = dst + (size_t)s * 32768 + t * 16;
#pragma unroll
    for (int j = 0; j < 8; ++j) {
        const int row = (j * 2 + rg0) * 16 + fr;
        *reinterpret_cast<i32x4*>(outp + j * 4096) =
            *reinterpret_cast<const i32x4*>(&lds[row][cc * 4]);
    }
}

// ---------------------------------------------------------------------------
// Batched i8 GEMM, fragment-linear loads (r15) + LDS-TRANSPOSE EPILOGUE.
//
// Tile 128x256, 512 thr = 8 waves 2x4, wave = 64x64 via 4x4 fragments of
// v_mfma_i32_16x16x64_i8, SWAPPED operands (lane fr=lane&15, kg=lane>>4
// holds C[m=..+fr][n=..+kg*4+r]). Loads: dense 1 KB bursts (r15: -11 us).
//
// NEW: stores were 16 rows x 64 B scattered segments per wave instruction
// (the same shape problem r15 fixed on loads, on the 4x-bigger stream).
// Epilogue now routes each mi-phase (4 phases, unrolled -> static acc
// indexing) through a 32 KB LDS tile: wave writes its scaled 16x64
// sub-tile (XOR-swizzled by row: byte ^= (row&7)<<4, keeps b128 LDS ops
// at the structural 8-cycle bank floor), barrier, then 512 threads read
// row-linear and store -> each wave store = ONE dense 1 KB run in a
// single output row (8 full 128 B lines, zero partial segments).
// Values pass through LDS bit-identically -> absmax stays 0.
//
// Grid 2048, chunked XCD swizzle (8 XCDs x 256, same-h resident slabs).
// Epilogue math (bit-exact): c = clamp(rint(acc*((sA[m]/sO[m])*sB[n])),
// -127, 127), stored as float32.
// ---------------------------------------------------------------------------
__global__ __launch_bounds__(512)
void gemm_i8_fused(const unsigned char* __restrict__ A8T,
                   const unsigned char* __restrict__ B8T,
                   const float* __restrict__ sA,
                   const float* __restrict__ sB,
                   const float* __restrict__ sO,
                   float* __restrict__ out) {
    __shared__ float lout[32 * 256];   // 32 KB epilogue staging

    // chunked XCD swizzle: nwg = 2048, 8 XCDs, 256 per chunk
    const int i = blockIdx.x;
    const int w = (i & 7) * 256 + (i >> 3);
    const int bx = w & 7;            // 8 col-tiles of 256
    const int by = (w >> 3) & 15;    // 16 row-tiles of 128
    const int h  = w >> 7;

    const int bm = by * 128;
    const int bn = bx * 256;
    const int tid  = threadIdx.x;
    const int wave = tid >> 6;
    const int lane = tid & 63;
    const int wm = (wave >> 2) * 64;   // 2 wave-rows of 64
    const int wn = (wave & 3) * 64;    // 4 wave-cols of 64
    const int fr = lane & 15;          // out row m sub-index
    const int kg = lane >> 4;          // out n-subchunk

    const unsigned char* AhT = A8T + (size_t)h * MDIM * KDIM;
    const unsigned char* BhT = B8T + (size_t)h * NDIM * KDIM;
    const int abase = (bm + wm) >> 4;  // rowgroup base for this wave's A rows
    const int bbase = (bn + wn) >> 4;  // rowgroup base for this wave's B rows

    i32x4 acc[4][4];
#pragma unroll
    for (int mi = 0; mi < 4; ++mi)
#pragma unroll
        for (int ni = 0; ni < 4; ++ni)
            acc[mi][ni] = (i32x4){0, 0, 0, 0};

#pragma unroll
    for (int ks = 0; ks < 2; ++ks) {
        i32x4 af[4], bf[4];
#pragma unroll
        for (int mi = 0; mi < 4; ++mi)
            af[mi] = *reinterpret_cast<const i32x4*>(
                AhT + (size_t)(abase + mi) * 2048 + ks * 1024 + lane * 16);
#pragma unroll
        for (int ni = 0; ni < 4; ++ni)
            bf[ni] = *reinterpret_cast<const i32x4*>(
                BhT + (size_t)(bbase + ni) * 2048 + ks * 1024 + lane * 16);
#pragma unroll
        for (int mi = 0; mi < 4; ++mi)
#pragma unroll
            for (int ni = 0; ni < 4; ++ni)
                acc[mi][ni] = __builtin_amdgcn_mfma_i32_16x16x64_i8(
                    bf[ni], af[mi], acc[mi][ni], 0, 0, 0);  // swapped -> C^T frag
    }

    // Scales (bit-exact reference op order).
    const float* sAh = sA + h * MDIM;
    const float* sBh = sB + h * NDIM;
    const float* sOh = sO + h * MDIM;

    float smv[4];
#pragma unroll
    for (int mi = 0; mi < 4; ++mi) {
        const int m = bm + wm + mi * 16 + fr;
        smv[mi] = sAh[m] / sOh[m];
    }
    f32x4 sbv[4];
#pragma unroll
    for (int ni = 0; ni < 4; ++ni)
        sbv[ni] = *reinterpret_cast<const f32x4*>(sBh + bn + wn + ni * 16 + kg * 4);

    // LDS-transpose epilogue: 4 phases (mi), fully unrolled.
    const int lrow = ((wave >> 2) << 4) + fr;     // 0..31 staging row
    char* lbase = reinterpret_cast<char*>(lout);
#pragma unroll
    for (int p = 0; p < 4; ++p) {
        // -- write: wave's scaled 16x64 sub-tile for mi=p --
#pragma unroll
        for (int ni = 0; ni < 4; ++ni) {
            f32x4 o;
#pragma unroll
            for (int r = 0; r < 4; ++r) {
                float c = (float)acc[p][ni][r] * (smv[p] * sbv[ni][r]);
                float rv = rintf(c);                       // RNE == np.round
                o[r] = fminf(fmaxf(rv, -127.0f), 127.0f);
            }
            const int colb = (wn + ni * 16 + kg * 4) * 4;  // byte col in row
            *reinterpret_cast<f32x4*>(
                lbase + lrow * 1024 + (colb ^ ((lrow & 7) << 4))) = o;
        }
        __syncthreads();
        // -- read row-linear + dense 1 KB wave stores --
#pragma unroll
        for (int j = 0; j < 4; ++j) {
            const int idx = j * 512 + tid;        // 0..2047 16B-chunks
            const int r2  = idx >> 6;             // staging row 0..31
            const int c16 = idx & 63;             // 16B chunk in row
            f32x4 v = *reinterpret_cast<const f32x4*>(
                lbase + r2 * 1024 + ((c16 * 16) ^ ((r2 & 7) << 4)));
            const int grow = bm + ((r2 >> 4) * 64) + p * 16 + (r2 & 15);
            *reinterpret_cast<f32x4*>(
                out + ((size_t)h * MDIM + grow) * NDIM + bn + c16 * 4) = v;
        }
        __syncthreads();
    }
}

extern "C" void kernel_launch(void* const* d_in, const int* in_sizes, int n_in,
                              void* d_out, int out_size, void* d_ws, size_t ws_size,
                              hipStream_t stream) {
    const int*   A  = (const int*)d_in[0];
    const int*   B  = (const int*)d_in[1];
    const float* sA = (const float*)d_in[2];
    const float* sB = (const float*)d_in[3];
    const float* sO = (const float*)d_in[4];
    float* out = (float*)d_out;

    unsigned char* A8T = (unsigned char*)d_ws;
    unsigned char* B8T = A8T + (size_t)HDIM * MDIM * KDIM;

    prep_relayout<<<256, 256, 0, stream>>>(
        A, B, sO, A8T, B8T, out + (size_t)HDIM * MDIM * NDIM);

    gemm_i8_fused<<<2048, 512, 0, stream>>>(A8T, B8T, sA, sB, sO, out);
}

// Round 17
// 69.004 us; speedup vs baseline: 3.9458x; 1.0239x over previous
//
#include <hip/hip_runtime.h>

typedef __attribute__((ext_vector_type(4))) int   i32x4;
typedef __attribute__((ext_vector_type(4))) float f32x4;

#define HDIM 16
#define MDIM 2048
#define NDIM 2048
#define KDIM 128

// Pack 4 int32 (values 0..126, high bytes zero) into one dword of 4 int8.
__device__ inline int pack4(i32x4 v) {
    return v.x | (v.y << 8) | (v.z << 16) | (v.w << 24);
}

// ---------------------------------------------------------------------------
// Prep v2 — fine-grained re-layout: pack int32 -> int8 into MFMA-fragment-
// linear order (per 16-row rowgroup: [ks=2][kg=4][fr=16][16B]).
//
// r15's prep ran 256 blocks = 4 waves/CU -> naked read latency (the r12
// signature, self-inflicted). Now 2048 blocks x 256 thr (16 waves/CU avg):
// block handles a 32-row slab (A: b<1024, slab s=b; B: s=b-1024).
//   read : thread t packs 16 int32 (64 B contiguous, 4x dwordx4) at
//          row r=t>>3, col (t&7)*16 -> 1x ds_write_b128 to lds[r][(t&7)*4].
//   write: thread t emits 16 B at dst + s*4096 + t*16, sourced from
//          lds[(t>>7)*16 + (t&15)][(((t>>6)&1)*4 + ((t>>4)&3))*4]
//          (fr=t&15, kg=(t>>4)&3, ks=(t>>6)&1, rg_local=t>>7) — matches the
//          GEMM's rowgrp*2048 + ks*1024 + lane*16 consumption exactly.
// LDS [32][36] padded: both phases at the 8-access/bank structural floor.
// Blocks b<128 also copy the scale_out passthrough tail.
// ---------------------------------------------------------------------------
__global__ __launch_bounds__(256)
void prep_relayout(const int* __restrict__ A,
                   const int* __restrict__ B,
                   const float* __restrict__ sO,
                   unsigned char* __restrict__ A8T,
                   unsigned char* __restrict__ B8T,
                   float* __restrict__ out_tail) {
    __shared__ int lds[32][36];

    const int b = blockIdx.x;
    const int t = threadIdx.x;

    const bool isB = (b >= 1024);
    const int s = isB ? (b - 1024) : b;           // 32-row slab id 0..1023
    const int* __restrict__ src = isB ? B : A;
    unsigned char* __restrict__ dst = isB ? B8T : A8T;

    if (b < 128) out_tail[b * 256 + t] = sO[b * 256 + t];

    // ---- read + pack: 64 B contiguous per thread ----
    const int r = t >> 3;          // 0..31 slab row
    const int q = t & 7;           // 16-int column chunk
    const i32x4* p = reinterpret_cast<const i32x4*>(
        src + (((size_t)s * 32 + r) * 128 + q * 16));
    i32x4 v0 = p[0], v1 = p[1], v2 = p[2], v3 = p[3];
    *reinterpret_cast<i32x4*>(&lds[r][q * 4]) =
        (i32x4){pack4(v0), pack4(v1), pack4(v2), pack4(v3)};
    __syncthreads();

    // ---- fragment-linear write: one dense 4 KB block run ----
    const int fr = t & 15, kg = (t >> 4) & 3, ks = (t >> 6) & 1, rg = t >> 7;
    const int cc = ks * 4 + kg;
    *reinterpret_cast<i32x4*>(dst + (size_t)s * 4096 + t * 16) =
        *reinterpret_cast<const i32x4*>(&lds[rg * 16 + fr][cc * 4]);
}

// ---------------------------------------------------------------------------
// Batched i8 GEMM (r16-proven, unchanged): fragment-linear 1 KB burst loads
// + LDS-transpose epilogue producing dense 1 KB row-linear store runs.
// Tile 128x256, 512 thr = 8 waves 2x4, wave = 64x64 via 4x4 fragments of
// v_mfma_i32_16x16x64_i8, SWAPPED operands (lane fr=lane&15, kg=lane>>4
// holds C[m=..+fr][n=..+kg*4+r]). Grid 2048, chunked XCD swizzle.
// Epilogue math (bit-exact): c = clamp(rint(acc*((sA[m]/sO[m])*sB[n])),
// -127, 127), stored as float32.
// ---------------------------------------------------------------------------
__global__ __launch_bounds__(512)
void gemm_i8_fused(const unsigned char* __restrict__ A8T,
                   const unsigned char* __restrict__ B8T,
                   const float* __restrict__ sA,
                   const float* __restrict__ sB,
                   const float* __restrict__ sO,
                   float* __restrict__ out) {
    __shared__ float lout[32 * 256];   // 32 KB epilogue staging

    // chunked XCD swizzle: nwg = 2048, 8 XCDs, 256 per chunk
    const int i = blockIdx.x;
    const int w = (i & 7) * 256 + (i >> 3);
    const int bx = w & 7;            // 8 col-tiles of 256
    const int by = (w >> 3) & 15;    // 16 row-tiles of 128
    const int h  = w >> 7;

    const int bm = by * 128;
    const int bn = bx * 256;
    const int tid  = threadIdx.x;
    const int wave = tid >> 6;
    const int lane = tid & 63;
    const int wm = (wave >> 2) * 64;   // 2 wave-rows of 64
    const int wn = (wave & 3) * 64;    // 4 wave-cols of 64
    const int fr = lane & 15;          // out row m sub-index
    const int kg = lane >> 4;          // out n-subchunk

    const unsigned char* AhT = A8T + (size_t)h * MDIM * KDIM;
    const unsigned char* BhT = B8T + (size_t)h * NDIM * KDIM;
    const int abase = (bm + wm) >> 4;  // rowgroup base for this wave's A rows
    const int bbase = (bn + wn) >> 4;  // rowgroup base for this wave's B rows

    i32x4 acc[4][4];
#pragma unroll
    for (int mi = 0; mi < 4; ++mi)
#pragma unroll
        for (int ni = 0; ni < 4; ++ni)
            acc[mi][ni] = (i32x4){0, 0, 0, 0};

#pragma unroll
    for (int ks = 0; ks < 2; ++ks) {
        i32x4 af[4], bf[4];
#pragma unroll
        for (int mi = 0; mi < 4; ++mi)
            af[mi] = *reinterpret_cast<const i32x4*>(
                AhT + (size_t)(abase + mi) * 2048 + ks * 1024 + lane * 16);
#pragma unroll
        for (int ni = 0; ni < 4; ++ni)
            bf[ni] = *reinterpret_cast<const i32x4*>(
                BhT + (size_t)(bbase + ni) * 2048 + ks * 1024 + lane * 16);
#pragma unroll
        for (int mi = 0; mi < 4; ++mi)
#pragma unroll
            for (int ni = 0; ni < 4; ++ni)
                acc[mi][ni] = __builtin_amdgcn_mfma_i32_16x16x64_i8(
                    bf[ni], af[mi], acc[mi][ni], 0, 0, 0);  // swapped -> C^T frag
    }

    // Scales (bit-exact reference op order).
    const float* sAh = sA + h * MDIM;
    const float* sBh = sB + h * NDIM;
    const float* sOh = sO + h * MDIM;

    float smv[4];
#pragma unroll
    for (int mi = 0; mi < 4; ++mi) {
        const int m = bm + wm + mi * 16 + fr;
        smv[mi] = sAh[m] / sOh[m];
    }
    f32x4 sbv[4];
#pragma unroll
    for (int ni = 0; ni < 4; ++ni)
        sbv[ni] = *reinterpret_cast<const f32x4*>(sBh + bn + wn + ni * 16 + kg * 4);

    // LDS-transpose epilogue: 4 phases (mi), fully unrolled.
    const int lrow = ((wave >> 2) << 4) + fr;     // 0..31 staging row
    char* lbase = reinterpret_cast<char*>(lout);
#pragma unroll
    for (int p = 0; p < 4; ++p) {
        // -- write: wave's scaled 16x64 sub-tile for mi=p --
#pragma unroll
        for (int ni = 0; ni < 4; ++ni) {
            f32x4 o;
#pragma unroll
            for (int r = 0; r < 4; ++r) {
                float c = (float)acc[p][ni][r] * (smv[p] * sbv[ni][r]);
                float rv = rintf(c);                       // RNE == np.round
                o[r] = fminf(fmaxf(rv, -127.0f), 127.0f);
            }
            const int colb = (wn + ni * 16 + kg * 4) * 4;  // byte col in row
            *reinterpret_cast<f32x4*>(
                lbase + lrow * 1024 + (colb ^ ((lrow & 7) << 4))) = o;
        }
        __syncthreads();
        // -- read row-linear + dense 1 KB wave stores --
#pragma unroll
        for (int j = 0; j < 4; ++j) {
            const int idx = j * 512 + tid;        // 0..2047 16B-chunks
            const int r2  = idx >> 6;             // staging row 0..31
            const int c16 = idx & 63;             // 16B chunk in row
            f32x4 v = *reinterpret_cast<const f32x4*>(
                lbase + r2 * 1024 + ((c16 * 16) ^ ((r2 & 7) << 4)));
            const int grow = bm + ((r2 >> 4) * 64) + p * 16 + (r2 & 15);
            *reinterpret_cast<f32x4*>(
                out + ((size_t)h * MDIM + grow) * NDIM + bn + c16 * 4) = v;
        }
        __syncthreads();
    }
}

extern "C" void kernel_launch(void* const* d_in, const int* in_sizes, int n_in,
                              void* d_out, int out_size, void* d_ws, size_t ws_size,
                              hipStream_t stream) {
    const int*   A  = (const int*)d_in[0];
    const int*   B  = (const int*)d_in[1];
    const float* sA = (const float*)d_in[2];
    const float* sB = (const float*)d_in[3];
    const float* sO = (const float*)d_in[4];
    float* out = (float*)d_out;

    unsigned char* A8T = (unsigned char*)d_ws;
    unsigned char* B8T = A8T + (size_t)HDIM * MDIM * KDIM;

    prep_relayout<<<2048, 256, 0, stream>>>(
        A, B, sO, A8T, B8T, out + (size_t)HDIM * MDIM * NDIM);

    gemm_i8_fused<<<2048, 512, 0, stream>>>(A8T, B8T, sA, sB, sO, out);
}

// Round 18
// 59.173 us; speedup vs baseline: 4.6014x; 1.1661x over previous
//
#include <hip/hip_runtime.h>

typedef __attribute__((ext_vector_type(4))) int   i32x4;
typedef __attribute__((ext_vector_type(4))) float f32x4;

#define HDIM 16
#define MDIM 2048
#define NDIM 2048
#define KDIM 128

// Pack 4 int32 (values 0..126, high bytes zero) into one dword of 4 int8.
__device__ inline int pack4(i32x4 v) {
    return v.x | (v.y << 8) | (v.z << 16) | (v.w << 24);
}

// ---------------------------------------------------------------------------
// Prep v3 — r17's fine-grained fragment-linear re-layout + XCD-ALIGNED
// slab assignment: with the chunked swizzle, XCD k packs exactly the A/B
// slabs ([128k,128k+128) each) that its own GEMM blocks (h=2k,2k+1) read.
// The packed 4 MB/XCD working set is thus born in the consuming XCD's L2;
// the GEMM's NT stores (below) no longer evict it -> GEMM reads = L2 hits.
//
// 2048 blocks x 256 thr; block handles a 32-row slab.
//   read : thread t packs 16 int32 (64 B contiguous) at row t>>3,
//          col (t&7)*16 -> 1x ds_write_b128 (lds[32][36], bank-floor).
//   write: thread t emits 16 B at dst + s*4096 + t*16 (dense 4 KB run),
//          sourced from lds[(t>>7)*16 + (t&15)][(((t>>6)&1)*4+((t>>4)&3))*4]
//          — matches the GEMM's rowgrp*2048 + ks*1024 + lane*16 exactly.
// Blocks i<128 also copy the scale_out passthrough tail.
// ---------------------------------------------------------------------------
__global__ __launch_bounds__(256)
void prep_relayout(const int* __restrict__ A,
                   const int* __restrict__ B,
                   const float* __restrict__ sO,
                   unsigned char* __restrict__ A8T,
                   unsigned char* __restrict__ B8T,
                   float* __restrict__ out_tail) {
    __shared__ int lds[32][36];

    const int i = blockIdx.x;
    const int t = threadIdx.x;

    // XCD-aligned chunked swizzle: XCD k = i&7 owns chunk u = i>>3 (0..255);
    // u<128 -> A slab 128k+u, else B slab 128k+(u-128).
    const int k = i & 7;
    const int u = i >> 3;
    const bool isB = (u >= 128);
    const int s = 128 * k + (isB ? (u - 128) : u);   // 32-row slab id 0..1023
    const int* __restrict__ src = isB ? B : A;
    unsigned char* __restrict__ dst = isB ? B8T : A8T;

    if (i < 128) out_tail[i * 256 + t] = sO[i * 256 + t];

    // ---- read + pack: 64 B contiguous per thread ----
    const int r = t >> 3;          // 0..31 slab row
    const int q = t & 7;           // 16-int column chunk
    const i32x4* p = reinterpret_cast<const i32x4*>(
        src + (((size_t)s * 32 + r) * 128 + q * 16));
    i32x4 v0 = p[0], v1 = p[1], v2 = p[2], v3 = p[3];
    *reinterpret_cast<i32x4*>(&lds[r][q * 4]) =
        (i32x4){pack4(v0), pack4(v1), pack4(v2), pack4(v3)};
    __syncthreads();

    // ---- fragment-linear write: one dense 4 KB block run ----
    const int fr = t & 15, kg = (t >> 4) & 3, ks = (t >> 6) & 1, rg = t >> 7;
    const int cc = ks * 4 + kg;
    *reinterpret_cast<i32x4*>(dst + (size_t)s * 4096 + t * 16) =
        *reinterpret_cast<const i32x4*>(&lds[rg * 16 + fr][cc * 4]);
}

// ---------------------------------------------------------------------------
// Batched i8 GEMM (r16 chassis): fragment-linear 1 KB burst loads +
// LDS-transpose epilogue -> dense 1 KB row-linear store runs, now issued
// NON-TEMPORALLY. NT is safe post-r16: each wave store covers 8 full 128-B
// lines (no partial-line RMW — r3's NT failure mode), and bypassing L2
// keeps the packed A/B working set resident for the 16x tile re-reads.
//
// Tile 128x256, 512 thr = 8 waves 2x4, wave = 64x64 via 4x4 fragments of
// v_mfma_i32_16x16x64_i8, SWAPPED operands (lane fr=lane&15, kg=lane>>4
// holds C[m=..+fr][n=..+kg*4+r]). Grid 2048, chunked XCD swizzle.
// Epilogue math (bit-exact): c = clamp(rint(acc*((sA[m]/sO[m])*sB[n])),
// -127, 127), stored as float32.
// ---------------------------------------------------------------------------
__global__ __launch_bounds__(512)
void gemm_i8_fused(const unsigned char* __restrict__ A8T,
                   const unsigned char* __restrict__ B8T,
                   const float* __restrict__ sA,
                   const float* __restrict__ sB,
                   const float* __restrict__ sO,
                   float* __restrict__ out) {
    __shared__ float lout[32 * 256];   // 32 KB epilogue staging

    // chunked XCD swizzle: nwg = 2048, 8 XCDs, 256 per chunk
    const int i = blockIdx.x;
    const int w = (i & 7) * 256 + (i >> 3);
    const int bx = w & 7;            // 8 col-tiles of 256
    const int by = (w >> 3) & 15;    // 16 row-tiles of 128
    const int h  = w >> 7;

    const int bm = by * 128;
    const int bn = bx * 256;
    const int tid  = threadIdx.x;
    const int wave = tid >> 6;
    const int lane = tid & 63;
    const int wm = (wave >> 2) * 64;   // 2 wave-rows of 64
    const int wn = (wave & 3) * 64;    // 4 wave-cols of 64
    const int fr = lane & 15;          // out row m sub-index
    const int kg = lane >> 4;          // out n-subchunk

    const unsigned char* AhT = A8T + (size_t)h * MDIM * KDIM;
    const unsigned char* BhT = B8T + (size_t)h * NDIM * KDIM;
    const int abase = (bm + wm) >> 4;  // rowgroup base for this wave's A rows
    const int bbase = (bn + wn) >> 4;  // rowgroup base for this wave's B rows

    i32x4 acc[4][4];
#pragma unroll
    for (int mi = 0; mi < 4; ++mi)
#pragma unroll
        for (int ni = 0; ni < 4; ++ni)
            acc[mi][ni] = (i32x4){0, 0, 0, 0};

#pragma unroll
    for (int ks = 0; ks < 2; ++ks) {
        i32x4 af[4], bf[4];
#pragma unroll
        for (int mi = 0; mi < 4; ++mi)
            af[mi] = *reinterpret_cast<const i32x4*>(
                AhT + (size_t)(abase + mi) * 2048 + ks * 1024 + lane * 16);
#pragma unroll
        for (int ni = 0; ni < 4; ++ni)
            bf[ni] = *reinterpret_cast<const i32x4*>(
                BhT + (size_t)(bbase + ni) * 2048 + ks * 1024 + lane * 16);
#pragma unroll
        for (int mi = 0; mi < 4; ++mi)
#pragma unroll
            for (int ni = 0; ni < 4; ++ni)
                acc[mi][ni] = __builtin_amdgcn_mfma_i32_16x16x64_i8(
                    bf[ni], af[mi], acc[mi][ni], 0, 0, 0);  // swapped -> C^T frag
    }

    // Scales (bit-exact reference op order).
    const float* sAh = sA + h * MDIM;
    const float* sBh = sB + h * NDIM;
    const float* sOh = sO + h * MDIM;

    float smv[4];
#pragma unroll
    for (int mi = 0; mi < 4; ++mi) {
        const int m = bm + wm + mi * 16 + fr;
        smv[mi] = sAh[m] / sOh[m];
    }
    f32x4 sbv[4];
#pragma unroll
    for (int ni = 0; ni < 4; ++ni)
        sbv[ni] = *reinterpret_cast<const f32x4*>(sBh + bn + wn + ni * 16 + kg * 4);

    // LDS-transpose epilogue: 4 phases (mi), fully unrolled.
    const int lrow = ((wave >> 2) << 4) + fr;     // 0..31 staging row
    char* lbase = reinterpret_cast<char*>(lout);
#pragma unroll
    for (int p = 0; p < 4; ++p) {
        // -- write: wave's scaled 16x64 sub-tile for mi=p --
#pragma unroll
        for (int ni = 0; ni < 4; ++ni) {
            f32x4 o;
#pragma unroll
            for (int r = 0; r < 4; ++r) {
                float c = (float)acc[p][ni][r] * (smv[p] * sbv[ni][r]);
                float rv = rintf(c);                       // RNE == np.round
                o[r] = fminf(fmaxf(rv, -127.0f), 127.0f);
            }
            const int colb = (wn + ni * 16 + kg * 4) * 4;  // byte col in row
            *reinterpret_cast<f32x4*>(
                lbase + lrow * 1024 + (colb ^ ((lrow & 7) << 4))) = o;
        }
        __syncthreads();
        // -- read row-linear + dense 1 KB NT wave stores (full lines) --
#pragma unroll
        for (int j = 0; j < 4; ++j) {
            const int idx = j * 512 + tid;        // 0..2047 16B-chunks
            const int r2  = idx >> 6;             // staging row 0..31
            const int c16 = idx & 63;             // 16B chunk in row
            f32x4 v = *reinterpret_cast<const f32x4*>(
                lbase + r2 * 1024 + ((c16 * 16) ^ ((r2 & 7) << 4)));
            const int grow = bm + ((r2 >> 4) * 64) + p * 16 + (r2 & 15);
            __builtin_nontemporal_store(v, reinterpret_cast<f32x4*>(
                out + ((size_t)h * MDIM + grow) * NDIM + bn + c16 * 4));
        }
        __syncthreads();
    }
}

extern "C" void kernel_launch(void* const* d_in, const int* in_sizes, int n_in,
                              void* d_out, int out_size, void* d_ws, size_t ws_size,
                              hipStream_t stream) {
    const int*   A  = (const int*)d_in[0];
    const int*   B  = (const int*)d_in[1];
    const float* sA = (const float*)d_in[2];
    const float* sB = (const float*)d_in[3];
    const float* sO = (const float*)d_in[4];
    float* out = (float*)d_out;

    unsigned char* A8T = (unsigned char*)d_ws;
    unsigned char* B8T = A8T + (size_t)HDIM * MDIM * KDIM;

    prep_relayout<<<2048, 256, 0, stream>>>(
        A, B, sO, A8T, B8T, out + (size_t)HDIM * MDIM * NDIM);

    gemm_i8_fused<<<2048, 512, 0, stream>>>(A8T, B8T, sA, sB, sO, out);
}